// Round 1
// baseline (1623.388 us; speedup 1.0000x reference)
//
#include <hip/hip_runtime.h>
#include <math.h>
#include <stdint.h>

#define NPOS 32768
#define LOG2N 15
#define BATCH 8

// ---------------- init: h0[b,c,n] = xs[n] + W0[c,0]*xs[n-1] + W0[c,1]*xs[n] + b0[c]
__global__ __launch_bounds__(256) void init_kernel(
    const int* __restrict__ x_int, const float* __restrict__ W0,
    const float* __restrict__ b0, float* __restrict__ h)
{
    int t = blockIdx.x * 256 + threadIdx.x;
    int n = t & (NPOS - 1);
    int b = t >> LOG2N;
    const int* xb = x_int + (size_t)b * NPOS;
    float xs  = (n >= 1) ? (float)xb[n - 1] * (1.f / 32768.f) : 0.f;
    float xsp = (n >= 2) ? (float)xb[n - 2] * (1.f / 32768.f) : 0.f;
    float* hb = h + ((size_t)b * 16) * NPOS + n;
#pragma unroll
    for (int c = 0; c < 16; ++c) {
        hb[(size_t)c * NPOS] = xs + W0[c * 2 + 0] * xsp + W0[c * 2 + 1] * xs + b0[c];
    }
}

// ---------------- one residual layer: f/g dilated conv + skip 1x1 + h update
__global__ __launch_bounds__(256) void layer_kernel(
    const float* __restrict__ hIn, float* __restrict__ hOut,
    float* __restrict__ skip,
    const float* __restrict__ wf, const float* __restrict__ bfv,
    const float* __restrict__ wg, const float* __restrict__ bgv,
    const float* __restrict__ wsk, const float* __restrict__ bskv,
    int d, int firstLayer)
{
    int t = blockIdx.x * 256 + threadIdx.x;
    int n = t & (NPOS - 1);
    int b = t >> LOG2N;
    const float* hb = hIn + ((size_t)b * 16) * NPOS + n;

    float hc[16], hp[16];
#pragma unroll
    for (int ic = 0; ic < 16; ++ic) hc[ic] = hb[(size_t)ic * NPOS];
    if (n >= d) {
#pragma unroll
        for (int ic = 0; ic < 16; ++ic) hp[ic] = hb[(size_t)ic * NPOS - (size_t)d];
    } else {
#pragma unroll
        for (int ic = 0; ic < 16; ++ic) hp[ic] = 0.f;
    }

    float facc[16], gacc[16];
#pragma unroll
    for (int c = 0; c < 16; ++c) { facc[c] = bfv[c]; gacc[c] = bgv[c]; }

#pragma unroll
    for (int c = 0; c < 16; ++c) {
#pragma unroll
        for (int ic = 0; ic < 16; ++ic) {
            facc[c] = fmaf(wf[(c * 16 + ic) * 2 + 0], hp[ic], facc[c]);
            facc[c] = fmaf(wf[(c * 16 + ic) * 2 + 1], hc[ic], facc[c]);
            gacc[c] = fmaf(wg[(c * 16 + ic) * 2 + 0], hp[ic], gacc[c]);
            gacc[c] = fmaf(wg[(c * 16 + ic) * 2 + 1], hc[ic], gacc[c]);
        }
    }

    // skip accumulation (uses pre-update h, as in reference)
    float* skb = skip + ((size_t)b * 32) * NPOS + n;
#pragma unroll
    for (int sc = 0; sc < 32; ++sc) {
        float acc = bskv[sc];
#pragma unroll
        for (int ic = 0; ic < 16; ++ic) acc = fmaf(wsk[sc * 16 + ic], hc[ic], acc);
        if (firstLayer) skb[(size_t)sc * NPOS] = acc;
        else            skb[(size_t)sc * NPOS] += acc;
    }

    float* ho = hOut + ((size_t)b * 16) * NPOS + n;
#pragma unroll
    for (int c = 0; c < 16; ++c) {
        float fv = tanhf(facc[c]);
        float gv = 1.f / (1.f + __expf(-gacc[c]));
        ho[(size_t)c * NPOS] = hc[c] + fv * gv;
    }
}

// ---------------- final: relu(skip) -> agg(64) -> relu -> logits(256) -> log_softmax
// block = 256 threads = 4 waves. Block covers 64 consecutive positions.
// Wave w (cg=w) computes classes [64w, 64w+64) for all 64 positions (lane = position).
__global__ __launch_bounds__(256) void final_kernel(
    const float* __restrict__ skip,
    const float* __restrict__ Wagg, const float* __restrict__ bagg,
    const float* __restrict__ Wout, const float* __restrict__ bout,
    float* __restrict__ out)
{
    __shared__ float red_m[64][4];
    __shared__ float red_s[64][4];

    int lane = threadIdx.x & 63;
    int cg = __builtin_amdgcn_readfirstlane((int)(threadIdx.x >> 6)); // wave-uniform class group
    size_t pos = (size_t)blockIdx.x * 64 + (size_t)lane;
    int n = (int)(pos & (NPOS - 1));
    int b = (int)(pos >> LOG2N);

    const float* skb = skip + ((size_t)b * 32) * NPOS + n;
    float sv[32];
#pragma unroll
    for (int sc = 0; sc < 32; ++sc) sv[sc] = fmaxf(skb[(size_t)sc * NPOS], 0.f);

    float agg[64];
#pragma unroll
    for (int a = 0; a < 64; ++a) {
        float acc = bagg[a];
#pragma unroll
        for (int sc = 0; sc < 32; ++sc) acc = fmaf(Wagg[a * 32 + sc], sv[sc], acc);
        agg[a] = fmaxf(acc, 0.f);
    }

    float lg[64];
    float m = -1e30f;
#pragma unroll
    for (int j = 0; j < 64; ++j) {
        int c = cg * 64 + j;
        float acc = bout[c];
#pragma unroll
        for (int ic = 0; ic < 64; ++ic) acc = fmaf(Wout[c * 64 + ic], agg[ic], acc);
        lg[j] = acc;
        m = fmaxf(m, acc);
    }

    float ssum = 0.f;
#pragma unroll
    for (int j = 0; j < 64; ++j) ssum += __expf(lg[j] - m);

    red_m[lane][cg] = m;
    red_s[lane][cg] = ssum;
    __syncthreads();

    float M = red_m[lane][0];
    M = fmaxf(M, red_m[lane][1]);
    M = fmaxf(M, red_m[lane][2]);
    M = fmaxf(M, red_m[lane][3]);
    float S = 0.f;
#pragma unroll
    for (int k = 0; k < 4; ++k) S += red_s[lane][k] * __expf(red_m[lane][k] - M);
    float logZ = M + __logf(S);

    float* ob = out + ((size_t)b * 256 + (size_t)cg * 64) * NPOS + n;
#pragma unroll
    for (int j = 0; j < 64; ++j) ob[(size_t)j * NPOS] = lg[j] - logZ;
}

extern "C" void kernel_launch(void* const* d_in, const int* in_sizes, int n_in,
                              void* d_out, int out_size, void* d_ws, size_t ws_size,
                              hipStream_t stream)
{
    const int*   x_int = (const int*)  d_in[0];
    const float* W0    = (const float*)d_in[1];
    const float* b0    = (const float*)d_in[2];
    const float* Wf    = (const float*)d_in[3];
    const float* bf    = (const float*)d_in[4];
    const float* Wg    = (const float*)d_in[5];
    const float* bg    = (const float*)d_in[6];
    const float* Wsk   = (const float*)d_in[7];
    const float* bsk   = (const float*)d_in[8];
    const float* Wagg  = (const float*)d_in[9];
    const float* bagg  = (const float*)d_in[10];
    const float* Wout  = (const float*)d_in[11];
    const float* bout  = (const float*)d_in[12];
    float* out = (float*)d_out;

    const size_t hElems  = (size_t)BATCH * 16 * NPOS; // 4M floats = 16 MiB
    const size_t skElems = (size_t)BATCH * 32 * NPOS; // 8M floats = 32 MiB

    float *skip, *hA, *hB;
    char* ws = (char*)d_ws;
    if (ws_size >= (hElems * 2 + skElems) * sizeof(float)) {
        skip = (float*)ws;
        hA   = (float*)(ws + skElems * sizeof(float));
        hB   = hA + hElems;
    } else if (ws_size >= skElems * sizeof(float)) {
        // h ping-pong lives in the tail of d_out (dead before final kernel writes it)
        skip = (float*)ws;
        hA   = out + ((size_t)out_size - 2 * hElems);
        hB   = hA + hElems;
    } else {
        // last resort (not expected): everything in out tail
        skip = out + ((size_t)out_size - skElems - 2 * hElems);
        hA   = skip + skElems;
        hB   = hA + hElems;
    }

    const int totalPos = BATCH * NPOS; // 262144

    init_kernel<<<totalPos / 256, 256, 0, stream>>>(x_int, W0, b0, hA);

    float* hin = hA;
    float* hout = hB;
    for (int i = 0; i < 19; ++i) {
        int d = 1 << ((i + 1) % 10);
        layer_kernel<<<totalPos / 256, 256, 0, stream>>>(
            hin, hout, skip,
            Wf + (size_t)i * 16 * 16 * 2, bf + (size_t)i * 16,
            Wg + (size_t)i * 16 * 16 * 2, bg + (size_t)i * 16,
            Wsk + (size_t)i * 32 * 16,    bsk + (size_t)i * 32,
            d, (i == 0) ? 1 : 0);
        float* tmp = hin; hin = hout; hout = tmp;
    }

    final_kernel<<<totalPos / 64, 256, 0, stream>>>(skip, Wagg, bagg, Wout, bout, out);
}